// Round 1
// baseline (490.125 us; speedup 1.0000x reference)
//
#include <hip/hip_runtime.h>
#include <type_traits>

#define N_ATOMS 256
#define N_MOL 4
#define N_PAIRS 8192
#define KE_C 14.3996
#define ALPHA_C 0.3
#define CUTOFF_C 6.0
#define JC_K 4   // kspace j-chunks of 64
#define JC_R 8   // real-space j-chunks of 32

constexpr double PI_D    = 3.14159265358979323846;
constexpr double TWOSQPI = 1.12837916709551257390; // 2/sqrt(pi)

// ---------------- dual numbers (forward-mode, for Hessian-vector product) ----
struct Dd {
  double v, t;
  __device__ Dd() {}
  __device__ Dd(double v_) : v(v_), t(0.0) {}
  __device__ Dd(double v_, double t_) : v(v_), t(t_) {}
};
__device__ inline Dd operator+(Dd a, Dd b){ return Dd(a.v+b.v, a.t+b.t); }
__device__ inline Dd operator+(double a, Dd b){ return Dd(a+b.v, b.t); }
__device__ inline Dd operator+(Dd a, double b){ return Dd(a.v+b, a.t); }
__device__ inline Dd operator-(Dd a, Dd b){ return Dd(a.v-b.v, a.t-b.t); }
__device__ inline Dd operator-(double a, Dd b){ return Dd(a-b.v, -b.t); }
__device__ inline Dd operator-(Dd a, double b){ return Dd(a.v-b, a.t); }
__device__ inline Dd operator-(Dd a){ return Dd(-a.v, -a.t); }
__device__ inline Dd operator*(Dd a, Dd b){ return Dd(a.v*b.v, a.t*b.v + a.v*b.t); }
__device__ inline Dd operator*(double a, Dd b){ return Dd(a*b.v, a*b.t); }
__device__ inline Dd operator*(Dd a, double b){ return Dd(a.v*b, a.t*b); }

__device__ inline double fsqrt(double a){ return sqrt(a); }
__device__ inline Dd     fsqrt(Dd a){ double s=sqrt(a.v); return Dd(s, a.t*0.5/s); }
__device__ inline double fexp(double a){ return exp(a); }
__device__ inline Dd     fexp(Dd a){ double e=exp(a.v); return Dd(e, a.t*e); }
__device__ inline double ferfc(double a){ return erfc(a); }
__device__ inline Dd     ferfc(Dd a){ return Dd(erfc(a.v), -a.t*TWOSQPI*exp(-a.v*a.v)); }
__device__ inline double ferf(double a){ return erf(a); }
__device__ inline Dd     ferf(Dd a){ return Dd(erf(a.v), a.t*TWOSQPI*exp(-a.v*a.v)); }
__device__ inline double finv(double a){ return 1.0/a; }
__device__ inline Dd     finv(Dd a){ double iv=1.0/a.v; return Dd(iv, -a.t*iv*iv); }
__device__ inline void fsincos(double a, double& s, double& c){ sincos(a, &s, &c); }
__device__ inline void fsincos(Dd a, Dd& s, Dd& c){
  double sv, cv; sincos(a.v, &sv, &cv); s = Dd(sv, a.t*cv); c = Dd(cv, -a.t*sv);
}
__device__ inline double fpown(double a, double e){ return pow(a, e); }
__device__ inline Dd     fpown(Dd a, double e){ double p=pow(a.v,e); return Dd(p, a.t*e*p/a.v); }
__device__ inline double gval(double a){ return a; }
__device__ inline double gval(Dd a){ return a.v; }
__device__ inline double pick(double a){ return a; }   // pass1: value of gradient
__device__ inline double pick(Dd a){ return a.t; }     // pass2: tangent = (H v)

template<class T> __device__ inline T loadP(const double* Rs, const double* V, int idx){
  if constexpr (std::is_same<T,double>::value) return Rs[idx];
  else return Dd(Rs[idx], V[idx]);
}
template<class T> __device__ inline T getT(const double* pv, const double* pt, int idx){
  if constexpr (std::is_same<T,double>::value) return pv[idx];
  else return Dd(pv[idx], pt[idx]);
}

__device__ inline double cell_area(const float* cell){
  double a0=cell[0], a1=cell[1], a2=cell[2];
  double b0=cell[3], b1=cell[4], b2=cell[5];
  double cx=a1*b2-a2*b1, cy=a2*b0-a0*b2, cz=a0*b1-a1*b0;
  return sqrt(cx*cx+cy*cy+cz*cz);
}

// ---------------- Rs0 = R + shift[mol]*film_mask ----------------------------
__global__ void prep_kernel(const float* R, const float* shiftv, const int* idx_m,
                            const int* is_film, double* Rs){
  int i = threadIdx.x;
  double mask = is_film[i] > 0 ? 1.0 : 0.0;
  int m = idx_m[i];
  for (int c = 0; c < 3; ++c)
    Rs[i*3+c] = (double)R[i*3+c] + mask*(double)shiftv[m*3+c];
}

// ---------------- Born: per-mol energy (pass1) + gradient / HVP -------------
template<class T>
__global__ void born_kernel(const double* Rs, const double* V,
                            const float* q, const float* offs, const float* r0a,
                            const float* na, const int* ii, const int* jj,
                            const int* im, double* dst, double* scal){
  constexpr bool P1 = std::is_same<T,double>::value;
  int p = blockIdx.x*blockDim.x + threadIdx.x;
  if (p >= N_PAIRS) return;
  int i = ii[p], j = jj[p];
  T rx = loadP<T>(Rs,V,j*3+0) - loadP<T>(Rs,V,i*3+0) + (double)offs[p*3+0];
  T ry = loadP<T>(Rs,V,j*3+1) - loadP<T>(Rs,V,i*3+1) + (double)offs[p*3+1];
  T rz = loadP<T>(Rs,V,j*3+2) - loadP<T>(Rs,V,i*3+2) + (double)offs[p*3+2];
  T dsq = rx*rx + ry*ry + rz*rz;
  T d = fsqrt(dsq);
  if (gval(d) < CUTOFF_C) {
    double qq = fabs((double)q[i]*(double)q[j]);
    double n  = (double)na[p];
    double B  = qq * pow((double)r0a[p], n-1.0) / n;
    T dmn = fpown(d, -n);
    if constexpr (P1) {
      double y = B*(gval(dmn) - pow(CUTOFF_C, -n));
      atomicAdd(&scal[3 + im[i]], 0.5*KE_C*y);
    }
    // dE/dRs_j = 0.5*KE * (-n B d^{-n-2}) r ;  dE/dRs_i = -that
    T c = (-0.5*KE_C*n*B) * (dmn * finv(dsq));
    T fx = c*rx, fy = c*ry, fz = c*rz;
    atomicAdd(&dst[j*3+0],  pick(fx));
    atomicAdd(&dst[j*3+1],  pick(fy));
    atomicAdd(&dst[j*3+2],  pick(fz));
    atomicAdd(&dst[i*3+0], -pick(fx));
    atomicAdd(&dst[i*3+1], -pick(fy));
    atomicAdd(&dst[i*3+2], -pick(fz));
  }
}

// ---------------- k-space S: energy + dS/dRs (x4*KEpi/2A folded) ------------
template<class T>
__global__ void kspace_kernel(const double* Rs, const double* V, const float* q,
                              const float* recipc, const float* cell,
                              double* dst, double* scal){
  constexpr bool P1 = std::is_same<T,double>::value;
  int blk = blockIdx.x;
  int kk = blk / JC_K, jc = blk % JC_K;
  int full = kk < 84 ? kk : kk + 1;        // skip (0,0) at raveled index 84
  double b0 = (double)(full/13 - 6);
  double b1 = (double)(full%13 - 6);
  const double TWO_PI = 2.0*PI_D;
  double h0 = TWO_PI*(b0*(double)recipc[0] + b1*(double)recipc[3]);
  double h1 = TWO_PI*(b0*(double)recipc[1] + b1*(double)recipc[4]);
  double h2 = TWO_PI*(b0*(double)recipc[2] + b1*(double)recipc[5]);
  double kap = sqrt(h0*h0 + h1*h1 + h2*h2);
  double A = kap/(2.0*ALPHA_C);
  double ikap = 1.0/kap;
  int i = threadIdx.x;
  __shared__ double sp[64*3];
  __shared__ double st[64*3];
  __shared__ double sqv[64];
  if (i < 64) {
    int j = jc*64 + i;
    sp[i*3+0]=Rs[j*3+0]; sp[i*3+1]=Rs[j*3+1]; sp[i*3+2]=Rs[j*3+2];
    sqv[i] = (double)q[j];
    if constexpr (!P1){ st[i*3+0]=V[j*3+0]; st[i*3+1]=V[j*3+1]; st[i*3+2]=V[j*3+2]; }
  }
  __syncthreads();
  T pix = loadP<T>(Rs,V,i*3+0);
  T piy = loadP<T>(Rs,V,i*3+1);
  T piz = loadP<T>(Rs,V,i*3+2);
  double qi = (double)q[i];
  T gx(0.0), gy(0.0), gz(0.0);
  double Sp = 0.0;
  for (int j2 = 0; j2 < 64; ++j2) {
    T rx = pix - getT<T>(sp,st,j2*3+0);
    T ry = piy - getT<T>(sp,st,j2*3+1);
    T rz = piz - getT<T>(sp,st,j2*3+2);
    T phase = h0*rx + h1*ry + h2*rz;
    T s, c; fsincos(phase, s, c);
    T ekz = fexp(kap*rz);
    T e1 = ekz * ferfc(A + ALPHA_C*rz);
    T e2 = finv(ekz) * ferfc(A - ALPHA_C*rz);
    double qq = qi * sqv[j2];
    T f = (e1 + e2) * ikap;                 // F
    if constexpr (P1) Sp += qq * gval(c) * gval(f);
    T cm  = (-2.0*qq) * (s * f);            // xy part: -2qq sin * F * h
    T czz = ( 2.0*qq) * (c * (e1 - e2));    // z part: F' = e1 - e2 (gaussians cancel)
    gx = gx + cm*h0;
    gy = gy + cm*h1;
    gz = gz + cm*h2 + czz;
  }
  double gs = 2.0*KE_C*PI_D/cell_area(cell);  // 4 * KE*pi/(2*area)
  atomicAdd(&dst[i*3+0], gs*pick(gx));
  atomicAdd(&dst[i*3+1], gs*pick(gy));
  atomicAdd(&dst[i*3+2], gs*pick(gz));
  if constexpr (P1) {
    __shared__ double red[256];
    red[i] = Sp; __syncthreads();
    for (int o = 128; o; o >>= 1){ if (i < o) red[i] += red[i+o]; __syncthreads(); }
    if (i == 0) atomicAdd(&scal[0], red[0]);
  }
}

// ---------------- S2 (z-only pairwise): energy + grad_z ---------------------
template<class T>
__global__ void s2_kernel(const double* Rs, const double* V, const float* q,
                          const float* cell, double* dst, double* scal){
  constexpr bool P1 = std::is_same<T,double>::value;
  int jc = blockIdx.x;   // 8 blocks, chunk of 32
  int i = threadIdx.x;
  __shared__ double sz[32], szt[32], sqv[32];
  if (i < 32) {
    int j = jc*32 + i;
    sz[i] = Rs[j*3+2]; sqv[i] = (double)q[j];
    if constexpr (!P1) szt[i] = V[j*3+2];
  }
  __syncthreads();
  T zi = loadP<T>(Rs,V,i*3+2);
  double qi = (double)q[i];
  T gzacc(0.0);
  double S2p = 0.0;
  const double IAS = 1.0/(ALPHA_C*sqrt(PI_D));
  for (int j2 = 0; j2 < 32; ++j2) {
    T z = zi - getT<T>(sz,szt,j2);
    double qq = qi * sqv[j2];
    T e = ferf(ALPHA_C*z);                  // g2'(z) = erf(a z)
    if constexpr (P1) {
      double zv = gval(z);
      S2p += qq*( zv*gval(e) + exp(-(ALPHA_C*zv)*(ALPHA_C*zv))*IAS );
    }
    gzacc = gzacc + qq*e;
  }
  double area = cell_area(cell);
  atomicAdd(&dst[i*3+2], (-8.0*KE_C*PI_D/area)*pick(gzacc)); // 4*(-KEpi/area)*2
  if constexpr (P1) {
    __shared__ double red[256];
    red[i] = S2p; __syncthreads();
    for (int o = 128; o; o >>= 1){ if (i < o) red[i] += red[i+o]; __syncthreads(); }
    if (i == 0) atomicAdd(&scal[1], red[0]);
  }
}

// ---------------- real-space: energy + gradient -----------------------------
template<class T>
__global__ void real_kernel(const double* Rs, const double* V, const float* q,
                            const float* cell, double* dst, double* scal){
  constexpr bool P1 = std::is_same<T,double>::value;
  int blk = blockIdx.x;
  int n = blk / JC_R, jc = blk % JC_R;       // n in [0,25), jc in [0,8)
  double n0 = (double)(n/5 - 2), n1 = (double)(n%5 - 2);
  double a0 = n0*(double)cell[0] + n1*(double)cell[3];
  double a1 = n0*(double)cell[1] + n1*(double)cell[4];
  double a2 = n0*(double)cell[2] + n1*(double)cell[5];
  int i = threadIdx.x;
  __shared__ double sp[32*3], st[32*3], sqv[32];
  if (i < 32) {
    int j = jc*32 + i;
    sp[i*3+0]=Rs[j*3+0]; sp[i*3+1]=Rs[j*3+1]; sp[i*3+2]=Rs[j*3+2];
    sqv[i] = (double)q[j];
    if constexpr (!P1){ st[i*3+0]=V[j*3+0]; st[i*3+1]=V[j*3+1]; st[i*3+2]=V[j*3+2]; }
  }
  __syncthreads();
  T pix = loadP<T>(Rs,V,i*3+0);
  T piy = loadP<T>(Rs,V,i*3+1);
  T piz = loadP<T>(Rs,V,i*3+2);
  double qi = (double)q[i];
  T gx(0.0), gy(0.0), gz(0.0);
  double Rp = 0.0;
  for (int j2 = 0; j2 < 32; ++j2) {
    T rx = pix - getT<T>(sp,st,j2*3+0) + a0;
    T ry = piy - getT<T>(sp,st,j2*3+1) + a1;
    T rz = piz - getT<T>(sp,st,j2*3+2) + a2;
    T dsq = rx*rx + ry*ry + rz*rz;
    if (gval(dsq) > 0.0) {
      double qq = qi * sqv[j2];
      T d = fsqrt(dsq);
      T ad = ALPHA_C*d;
      T ec = ferfc(ad);
      T invd = finv(d);
      if constexpr (P1) Rp += qq*gval(ec)*gval(invd);
      T expt = fexp(-(ad*ad));
      // phi'(d) = -(2a/sqrt(pi)) e^{-a^2 d^2}/d - erfc(ad)/d^2
      T phip = -( (TWOSQPI*ALPHA_C)*expt*invd + ec*invd*invd );
      T coef = qq*(phip*invd);
      gx = gx + coef*rx; gy = gy + coef*ry; gz = gz + coef*rz;
    }
  }
  atomicAdd(&dst[i*3+0], 4.0*KE_C*pick(gx));
  atomicAdd(&dst[i*3+1], 4.0*KE_C*pick(gy));
  atomicAdd(&dst[i*3+2], 4.0*KE_C*pick(gz));
  if constexpr (P1) {
    __shared__ double red[256];
    red[i] = Rp; __syncthreads();
    for (int o = 128; o; o >>= 1){ if (i < o) red[i] += red[i+o]; __syncthreads(); }
    if (i == 0) atomicAdd(&scal[2], red[0]);
  }
}

// ---------------- finish pass1: energies, ff, ffn, v ------------------------
__global__ void finish1_kernel(const double* g, const double* scal, const float* q,
                               const float* cell, const int* im, const int* film,
                               double* V, float* out){
  int i = threadIdx.x;
  __shared__ double ffsh[12];
  if (i < 12) {
    int mm = i/3, c = i%3;
    double s = 0.0;
    for (int a = 0; a < N_ATOMS; ++a)
      if (im[a] == mm && film[a] > 0) s -= g[a*3+c];
    ffsh[i] = s;
  }
  __syncthreads();
  {
    double mask = film[i] > 0 ? 1.0 : 0.0;
    int m = im[i];
    V[i*3+0] = mask*ffsh[m*3+0];
    V[i*3+1] = mask*ffsh[m*3+1];
    V[i*3+2] = mask*ffsh[m*3+2];
  }
  if (i == 0) {
    double qs = 0.0;
    for (int a = 0; a < N_ATOMS; ++a){ double qa=(double)q[a]; qs += qa*qa; }
    double area = cell_area(cell);
    double S = scal[0], S2 = scal[1], RR = scal[2];
    double recip = KE_C*PI_D*(S/(2.0*area) - S2/area);
    double realE = 0.5*KE_C*RR;
    double selfE = -ALPHA_C/sqrt(PI_D)*qs*KE_C;
    double Ec = recip + realE + selfE;
    out[4] = (float)Ec;
    for (int m = 0; m < 4; ++m) {
      double yb = scal[3+m];
      out[5+m] = (float)yb;
      out[m]   = (float)(Ec + yb);
    }
  }
  if (i < 4) {
    double f0 = ffsh[i*3+0], f1 = ffsh[i*3+1], f2 = ffsh[i*3+2];
    out[9+i] = (float)(f0*f0 + f1*f1 + f2*f2);
  }
}

// ---------------- finish pass2: fng = -2 * segsum(mask * Hv) ----------------
__global__ void finish2_kernel(const double* w, const int* im, const int* film,
                               float* out){
  int i = threadIdx.x;
  if (i < 12) {
    int mm = i/3, c = i%3;
    double s = 0.0;
    for (int a = 0; a < N_ATOMS; ++a)
      if (im[a] == mm && film[a] > 0) s += w[a*3+c];
    out[13+i] = (float)(-2.0*s);
  }
}

extern "C" void kernel_launch(void* const* d_in, const int* in_sizes, int n_in,
                              void* d_out, int out_size, void* d_ws, size_t ws_size,
                              hipStream_t stream){
  const float* R      = (const float*)d_in[0];
  const float* shiftv = (const float*)d_in[1];
  const float* q      = (const float*)d_in[2];
  const float* offs   = (const float*)d_in[3];
  const float* cell   = (const float*)d_in[4];
  const float* recipc = (const float*)d_in[5];
  const float* r0a    = (const float*)d_in[6];
  const float* na     = (const float*)d_in[7];
  const int*   ii     = (const int*)d_in[8];
  const int*   jj     = (const int*)d_in[9];
  const int*   im     = (const int*)d_in[10];
  const int*   film   = (const int*)d_in[11];
  float* out = (float*)d_out;

  double* ws   = (double*)d_ws;
  double* Rs   = ws;            // 768
  double* g    = ws + 768;      // 768 (total gradient: born + 4*coulomb)
  double* w    = ws + 1536;     // 768 (H v)
  double* V    = ws + 2304;     // 768 (tangent vector v)
  double* scal = ws + 3072;     // [0]=S [1]=S2 [2]=real_raw [3..6]=born_mol

  hipMemsetAsync(d_ws, 0, 3080*sizeof(double), stream);
  hipLaunchKernelGGL(prep_kernel, dim3(1), dim3(256), 0, stream, R, shiftv, im, film, Rs);

  // pass 1: energies + gradient
  hipLaunchKernelGGL((born_kernel<double>),   dim3(N_PAIRS/256), dim3(256), 0, stream,
                     Rs, V, q, offs, r0a, na, ii, jj, im, g, scal);
  hipLaunchKernelGGL((kspace_kernel<double>), dim3(168*JC_K), dim3(256), 0, stream,
                     Rs, V, q, recipc, cell, g, scal);
  hipLaunchKernelGGL((s2_kernel<double>),     dim3(8), dim3(256), 0, stream,
                     Rs, V, q, cell, g, scal);
  hipLaunchKernelGGL((real_kernel<double>),   dim3(25*JC_R), dim3(256), 0, stream,
                     Rs, V, q, cell, g, scal);
  hipLaunchKernelGGL(finish1_kernel, dim3(1), dim3(256), 0, stream,
                     g, scal, q, cell, im, film, V, out);

  // pass 2: Hessian-vector product via dual numbers (tangent = v)
  hipLaunchKernelGGL((born_kernel<Dd>),   dim3(N_PAIRS/256), dim3(256), 0, stream,
                     Rs, V, q, offs, r0a, na, ii, jj, im, w, scal);
  hipLaunchKernelGGL((kspace_kernel<Dd>), dim3(168*JC_K), dim3(256), 0, stream,
                     Rs, V, q, recipc, cell, w, scal);
  hipLaunchKernelGGL((s2_kernel<Dd>),     dim3(8), dim3(256), 0, stream,
                     Rs, V, q, cell, w, scal);
  hipLaunchKernelGGL((real_kernel<Dd>),   dim3(25*JC_R), dim3(256), 0, stream,
                     Rs, V, q, cell, w, scal);
  hipLaunchKernelGGL(finish2_kernel, dim3(1), dim3(256), 0, stream,
                     w, im, film, out);
}

// Round 2
// 197.710 us; speedup vs baseline: 2.4790x; 2.4790x over previous
//
#include <hip/hip_runtime.h>
#include <type_traits>

#define N_ATOMS 256
#define N_MOL 4
#define N_PAIRS 8192
#define KE_C 14.3996
#define ALPHA_C 0.3
#define CUTOFF_C 6.0

constexpr double PI_D    = 3.14159265358979323846;
constexpr double TWOSQPI = 1.12837916709551257390; // 2/sqrt(pi)
#define AL_F 0.3f
#define TWOSQPI_F 1.12837917f
#define K1_F 0.33851375f   // TWOSQPI*ALPHA

// ---------------- fast fp32 erfc (NR 6.2, rel err ~1e-6 with __expf) --------
__device__ __forceinline__ float fast_erfcf(float x){
  float ax = fabsf(x);
  float t = __fdividef(1.0f, fmaf(0.5f, ax, 1.0f));
  float p = 0.17087277f;
  p = fmaf(p, t, -0.82215223f);
  p = fmaf(p, t,  1.48851587f);
  p = fmaf(p, t, -1.13520398f);
  p = fmaf(p, t,  0.27886807f);
  p = fmaf(p, t, -0.18628806f);
  p = fmaf(p, t,  0.09678418f);
  p = fmaf(p, t,  0.37409196f);
  p = fmaf(p, t,  1.00002368f);
  p = fmaf(p, t, -1.26551223f);
  float ans = t*__expf(fmaf(-ax, ax, p));
  return x >= 0.0f ? ans : 2.0f - ans;
}

// ---------------- dual numbers (fp64, for Born/S2 HVP) ----------------------
struct Dd {
  double v, t;
  __device__ Dd() {}
  __device__ Dd(double v_) : v(v_), t(0.0) {}
  __device__ Dd(double v_, double t_) : v(v_), t(t_) {}
};
__device__ inline Dd operator+(Dd a, Dd b){ return Dd(a.v+b.v, a.t+b.t); }
__device__ inline Dd operator+(double a, Dd b){ return Dd(a+b.v, b.t); }
__device__ inline Dd operator+(Dd a, double b){ return Dd(a.v+b, a.t); }
__device__ inline Dd operator-(Dd a, Dd b){ return Dd(a.v-b.v, a.t-b.t); }
__device__ inline Dd operator-(double a, Dd b){ return Dd(a-b.v, -b.t); }
__device__ inline Dd operator-(Dd a, double b){ return Dd(a.v-b, a.t); }
__device__ inline Dd operator-(Dd a){ return Dd(-a.v, -a.t); }
__device__ inline Dd operator*(Dd a, Dd b){ return Dd(a.v*b.v, a.t*b.v + a.v*b.t); }
__device__ inline Dd operator*(double a, Dd b){ return Dd(a*b.v, a*b.t); }
__device__ inline Dd operator*(Dd a, double b){ return Dd(a.v*b, a.t*b); }

__device__ inline double fsqrt(double a){ return sqrt(a); }
__device__ inline Dd     fsqrt(Dd a){ double s=sqrt(a.v); return Dd(s, a.t*0.5/s); }
__device__ inline double fexp(double a){ return exp(a); }
__device__ inline Dd     fexp(Dd a){ double e=exp(a.v); return Dd(e, a.t*e); }
__device__ inline double ferf(double a){ return erf(a); }
__device__ inline Dd     ferf(Dd a){ return Dd(erf(a.v), a.t*TWOSQPI*exp(-a.v*a.v)); }
__device__ inline double finv(double a){ return 1.0/a; }
__device__ inline Dd     finv(Dd a){ double iv=1.0/a.v; return Dd(iv, -a.t*iv*iv); }
__device__ inline double fpown(double a, double e){ return pow(a, e); }
__device__ inline Dd     fpown(Dd a, double e){ double p=pow(a.v,e); return Dd(p, a.t*e*p/a.v); }
__device__ inline double gval(double a){ return a; }
__device__ inline double gval(Dd a){ return a.v; }
__device__ inline double pick(double a){ return a; }   // pass1: gradient value
__device__ inline double pick(Dd a){ return a.t; }     // pass2: tangent = H v

template<class T> __device__ inline T loadP(const double* Rs, const double* V, int idx){
  if constexpr (std::is_same<T,double>::value) return Rs[idx];
  else return Dd(Rs[idx], V[idx]);
}
template<class T> __device__ inline T getT(const double* pv, const double* pt, int idx){
  if constexpr (std::is_same<T,double>::value) return pv[idx];
  else return Dd(pv[idx], pt[idx]);
}

__device__ inline double cell_area(const float* cell){
  double a0=cell[0], a1=cell[1], a2=cell[2];
  double b0=cell[3], b1=cell[4], b2=cell[5];
  double cx=a1*b2-a2*b1, cy=a2*b0-a0*b2, cz=a0*b1-a1*b0;
  return sqrt(cx*cx+cy*cy+cz*cz);
}

// ---------------- Rs0 = R + shift[mol]*film_mask ----------------------------
__global__ void prep_kernel(const float* R, const float* shiftv, const int* idx_m,
                            const int* is_film, double* Rs){
  int i = threadIdx.x;
  double mask = is_film[i] > 0 ? 1.0 : 0.0;
  int m = idx_m[i];
  for (int c = 0; c < 3; ++c)
    Rs[i*3+c] = (double)R[i*3+c] + mask*(double)shiftv[m*3+c];
}

// ---------------- per-(k,atom) table: cos, sin, exp(kz), exp(-kz) -----------
__global__ void ktab_kernel(const double* Rs, const float* recipc, float4* tab){
  int kk = blockIdx.x;      // 0..83  (b0,b1); negatives folded with x2
  int a  = threadIdx.x;
  double b0 = (double)(kk/13 - 6), b1 = (double)(kk%13 - 6);
  double TP = 2.0*PI_D;
  double h0 = TP*(b0*(double)recipc[0] + b1*(double)recipc[3]);
  double h1 = TP*(b0*(double)recipc[1] + b1*(double)recipc[4]);
  double h2 = TP*(b0*(double)recipc[2] + b1*(double)recipc[5]);
  double kap = sqrt(h0*h0 + h1*h1 + h2*h2);
  double x = Rs[a*3+0], y = Rs[a*3+1], z = Rs[a*3+2];
  double phi = h0*x + h1*y + h2*z;
  double s, c; sincos(phi, &s, &c);
  double E = exp(kap*z);
  tab[kk*256+a] = make_float4((float)c, (float)s, (float)E, (float)(1.0/E));
}

// ---------------- Born body (fp64 / dual) -----------------------------------
template<class T>
__device__ void born_body(int p, const double* Rs, const double* V, const float* q,
                          const float* offs, const float* r0a, const float* na,
                          const int* ii, const int* jj, const int* im,
                          double* dst, double* scal){
  constexpr bool P1 = std::is_same<T,double>::value;
  int i = ii[p], j = jj[p];
  T rx = loadP<T>(Rs,V,j*3+0) - loadP<T>(Rs,V,i*3+0) + (double)offs[p*3+0];
  T ry = loadP<T>(Rs,V,j*3+1) - loadP<T>(Rs,V,i*3+1) + (double)offs[p*3+1];
  T rz = loadP<T>(Rs,V,j*3+2) - loadP<T>(Rs,V,i*3+2) + (double)offs[p*3+2];
  T dsq = rx*rx + ry*ry + rz*rz;
  T d = fsqrt(dsq);
  if (gval(d) < CUTOFF_C) {
    double qq = fabs((double)q[i]*(double)q[j]);
    double n  = (double)na[p];
    double B  = qq * pow((double)r0a[p], n-1.0) / n;
    T dmn = fpown(d, -n);
    if constexpr (P1) {
      double y = B*(gval(dmn) - pow(CUTOFF_C, -n));
      atomicAdd(&scal[3 + im[i]], 0.5*KE_C*y);
    }
    T c = (-0.5*KE_C*n*B) * (dmn * finv(dsq));
    T fx = c*rx, fy = c*ry, fz = c*rz;
    atomicAdd(&dst[j*3+0],  pick(fx));
    atomicAdd(&dst[j*3+1],  pick(fy));
    atomicAdd(&dst[j*3+2],  pick(fz));
    atomicAdd(&dst[i*3+0], -pick(fx));
    atomicAdd(&dst[i*3+1], -pick(fy));
    atomicAdd(&dst[i*3+2], -pick(fz));
  }
}

// ---------------- S2 body (fp64 / dual) -------------------------------------
template<class T>
__device__ void s2_body(int jc, const double* Rs, const double* V, const float* q,
                        const float* cell, double* dst, double* scal){
  constexpr bool P1 = std::is_same<T,double>::value;
  int i = threadIdx.x;
  __shared__ double sz[32], szt[32], sqv[32];
  if (i < 32) {
    int j = jc*32 + i;
    sz[i] = Rs[j*3+2]; sqv[i] = (double)q[j];
    if constexpr (!P1) szt[i] = V[j*3+2]; else szt[i] = 0.0;
  }
  __syncthreads();
  T zi = loadP<T>(Rs,V,i*3+2);
  double qi = (double)q[i];
  T gzacc(0.0);
  double S2p = 0.0;
  const double IAS = 1.0/(ALPHA_C*sqrt(PI_D));
  for (int j2 = 0; j2 < 32; ++j2) {
    T z = zi - getT<T>(sz,szt,j2);
    double qq = qi * sqv[j2];
    T e = ferf(ALPHA_C*z);
    if constexpr (P1) {
      double zv = gval(z);
      S2p += qq*( zv*gval(e) + exp(-(ALPHA_C*zv)*(ALPHA_C*zv))*IAS );
    }
    gzacc = gzacc + qq*e;
  }
  double area = cell_area(cell);
  atomicAdd(&dst[i*3+2], (-8.0*KE_C*PI_D/area)*pick(gzacc));
  if constexpr (P1) {
    __shared__ double red[256];
    red[i] = S2p; __syncthreads();
    for (int o = 128; o; o >>= 1){ if (i < o) red[i] += red[i+o]; __syncthreads(); }
    if (i == 0) atomicAdd(&scal[1], red[0]);
  }
}

// ---------------- merged pass kernels ---------------------------------------
// blocks: [0,672) kspace (kk = b>>3, jc = b&7, 32 j each)
//         [672,872) real (n = r>>3, jc = r&7)
//         [872,904) born ; [904,912) s2
#define KS_B 672
#define RE_B 200
#define BO_B 32
#define S2_B 8

template<bool PASS2>
__global__ __launch_bounds__(256) void pass_kernel(
    const double* Rs, const double* V, const float* q,
    const float* offs, const float* r0a, const float* na,
    const int* ii, const int* jj, const int* im,
    const float* recipc, const float* cell, const float4* tab,
    double* gbase, double* scal){
  int b = blockIdx.x;
  double* g = gbase + (b & 7)*768;
  int i = threadIdx.x;
  if (b < KS_B) {
    int kk = b >> 3, jc = b & 7;
    double b0 = (double)(kk/13 - 6), b1d = (double)(kk%13 - 6);
    double TP = 2.0*PI_D;
    double h0d = TP*(b0*(double)recipc[0] + b1d*(double)recipc[3]);
    double h1d = TP*(b0*(double)recipc[1] + b1d*(double)recipc[4]);
    double h2d = TP*(b0*(double)recipc[2] + b1d*(double)recipc[5]);
    double kapd = sqrt(h0d*h0d + h1d*h1d + h2d*h2d);
    float A    = (float)(kapd/(2.0*ALPHA_C));
    float ikap = (float)(1.0/kapd);
    float kapf = (float)kapd;
    __shared__ float kcj[32], ksj[32], kEj[32], kiEj[32], kzj[32], kqj[32];
    __shared__ float kdpj[32], kvzj[32];
    if (i < 32) {
      int j = jc*32 + i;
      float4 t = tab[kk*256+j];
      kcj[i]=t.x; ksj[i]=t.y; kEj[i]=t.z; kiEj[i]=t.w;
      kzj[i]=(float)Rs[j*3+2]; kqj[i]=q[j];
      if constexpr (PASS2) {
        kdpj[i] = (float)(h0d*V[j*3+0] + h1d*V[j*3+1] + h2d*V[j*3+2]);
        kvzj[i] = (float)V[j*3+2];
      }
    }
    __syncthreads();
    float4 ti = tab[kk*256+i];
    float ci=ti.x, si=ti.y, Ei=ti.z, iEi=ti.w;
    float zi=(float)Rs[i*3+2], qi=q[i];
    float dpi=0.f, vzi=0.f;
    if constexpr (PASS2) {
      dpi = (float)(h0d*V[i*3+0] + h1d*V[i*3+1] + h2d*V[i*3+2]);
      vzi = (float)V[i*3+2];
    }
    double Sp=0.0, cmS=0.0, czS=0.0;
    #pragma unroll 4
    for (int j2=0;j2<32;++j2){
      float z  = zi - kzj[j2];
      float az = AL_F*z;
      float u1 = A + az, u2 = A - az;
      float ec1 = fast_erfcf(u1), ec2 = fast_erfcf(u2);
      float ekz = Ei*kiEj[j2], ikz = iEi*kEj[j2];
      float e1 = ekz*ec1, e2 = ikz*ec2;
      float cph = ci*kcj[j2] + si*ksj[j2];
      float sph = si*kcj[j2] - ci*ksj[j2];
      float fF  = (e1+e2)*ikap;
      float qq  = qi*kqj[j2];
      if constexpr (!PASS2) {
        Sp  += (double)(qq*cph*fF);
        cmS += (double)(-2.0f*qq*sph*fF);
        czS += (double)( 2.0f*qq*cph*(e1-e2));
      } else {
        float dz   = vzi - kvzj[j2];
        float dphi = dpi - kdpj[j2];
        float g1 = TWOSQPI_F*__expf(-u1*u1);
        float g2 = TWOSQPI_F*__expf(-u2*u2);
        float de1 = dz*(kapf*e1 - AL_F*ekz*g1);
        float de2 = dz*(AL_F*ikz*g2 - kapf*e2);
        float dF  = (de1+de2)*ikap;
        float dcs = -sph*dphi, dsn = cph*dphi;
        cmS += (double)(-2.0f*qq*(dsn*fF + sph*dF));
        czS += (double)( 2.0f*qq*(dcs*(e1-e2) + cph*(de1-de2)));
      }
    }
    double area = cell_area(cell);
    double gsc = 4.0*KE_C*PI_D/area;   // (2 KE pi/area) * 2 for +-k fold
    atomicAdd(&g[i*3+0], gsc*(h0d*cmS));
    atomicAdd(&g[i*3+1], gsc*(h1d*cmS));
    atomicAdd(&g[i*3+2], gsc*(h2d*cmS + czS));
    if constexpr (!PASS2) {
      __shared__ double kred[256];
      kred[i] = Sp; __syncthreads();
      for (int o=128;o;o>>=1){ if (i<o) kred[i]+=kred[i+o]; __syncthreads(); }
      if (i==0) atomicAdd(&scal[0], 2.0*kred[0]);
    }
  } else if (b < KS_B + RE_B) {
    int r = b - KS_B; int nn = r >> 3, jc = r & 7;
    double n0 = (double)(nn/5 - 2), n1 = (double)(nn%5 - 2);
    float a0 = (float)(n0*(double)cell[0] + n1*(double)cell[3]);
    float a1 = (float)(n0*(double)cell[1] + n1*(double)cell[4]);
    float a2 = (float)(n0*(double)cell[2] + n1*(double)cell[5]);
    __shared__ float rpx[32], rpy[32], rpz[32], rq[32];
    __shared__ float rvx[32], rvy[32], rvz[32];
    if (i<32){
      int j = jc*32+i;
      rpx[i]=(float)Rs[j*3+0]; rpy[i]=(float)Rs[j*3+1]; rpz[i]=(float)Rs[j*3+2];
      rq[i]=q[j];
      if constexpr (PASS2){
        rvx[i]=(float)V[j*3+0]; rvy[i]=(float)V[j*3+1]; rvz[i]=(float)V[j*3+2];
      }
    }
    __syncthreads();
    float xi=(float)Rs[i*3+0], yi=(float)Rs[i*3+1], zi=(float)Rs[i*3+2], qi=q[i];
    float vxi=0.f, vyi=0.f, vzi=0.f;
    if constexpr (PASS2){
      vxi=(float)V[i*3+0]; vyi=(float)V[i*3+1]; vzi=(float)V[i*3+2];
    }
    double gx=0,gy=0,gz=0,Rp=0;
    for (int j2=0;j2<32;++j2){
      float rx = xi - rpx[j2] + a0;
      float ry = yi - rpy[j2] + a1;
      float rz = zi - rpz[j2] + a2;
      float dsq = rx*rx+ry*ry+rz*rz;
      if (dsq > 0.0f){
        float d = sqrtf(dsq);
        float invd = __fdividef(1.0f, d);
        float ad = AL_F*d;
        float ec = fast_erfcf(ad);
        float ex = __expf(-ad*ad);
        float qq = qi*rq[j2];
        float P  = -(K1_F*ex*invd + ec*invd*invd);
        float C  = qq*P*invd;
        if constexpr (!PASS2) {
          Rp += (double)(qq*ec*invd);
          gx += (double)(C*rx); gy += (double)(C*ry); gz += (double)(C*rz);
        } else {
          float drx = vxi - rvx[j2], dry = vyi - rvy[j2], drz = vzi - rvz[j2];
          float dd  = (rx*drx + ry*dry + rz*drz)*invd;
          float invd2 = invd*invd;
          float dC = qq*dd*( K1_F*ex*(2.0f*AL_F*AL_F + 3.0f*invd2)*invd
                             + 3.0f*ec*invd2*invd2 );
          gx += (double)(dC*rx + C*drx);
          gy += (double)(dC*ry + C*dry);
          gz += (double)(dC*rz + C*drz);
        }
      }
    }
    atomicAdd(&g[i*3+0], 4.0*KE_C*gx);
    atomicAdd(&g[i*3+1], 4.0*KE_C*gy);
    atomicAdd(&g[i*3+2], 4.0*KE_C*gz);
    if constexpr (!PASS2) {
      __shared__ double rred[256];
      rred[i] = Rp; __syncthreads();
      for (int o=128;o;o>>=1){ if (i<o) rred[i]+=rred[i+o]; __syncthreads(); }
      if (i==0) atomicAdd(&scal[2], rred[0]);
    }
  } else if (b < KS_B + RE_B + BO_B) {
    int p = (b - KS_B - RE_B)*256 + i;
    if constexpr (!PASS2)
      born_body<double>(p, Rs, V, q, offs, r0a, na, ii, jj, im, g, scal);
    else
      born_body<Dd>(p, Rs, V, q, offs, r0a, na, ii, jj, im, g, scal);
  } else {
    int jc = b - KS_B - RE_B - BO_B;
    if constexpr (!PASS2)
      s2_body<double>(jc, Rs, V, q, cell, g, scal);
    else
      s2_body<Dd>(jc, Rs, V, q, cell, g, scal);
  }
}

// ---------------- finish pass1: energies, ff, ffn, v ------------------------
__global__ void finish1_kernel(const double* g8, const double* scal, const float* q,
                               const float* cell, const int* im, const int* film,
                               double* V, float* out){
  int i = threadIdx.x;
  __shared__ double gsh[256][3];
  double s0=0,s1=0,s2v=0;
  for (int c=0;c<8;++c){
    const double* g = g8 + c*768;
    s0 += g[i*3+0]; s1 += g[i*3+1]; s2v += g[i*3+2];
  }
  gsh[i][0]=s0; gsh[i][1]=s1; gsh[i][2]=s2v;
  __syncthreads();
  __shared__ double ffsh[12];
  if (i < 12) {
    int mm = i/3, c = i%3;
    double s = 0.0;
    for (int a = 0; a < N_ATOMS; ++a)
      if (im[a] == mm && film[a] > 0) s -= gsh[a][c];
    ffsh[i] = s;
  }
  __syncthreads();
  {
    double mask = film[i] > 0 ? 1.0 : 0.0;
    int m = im[i];
    V[i*3+0] = mask*ffsh[m*3+0];
    V[i*3+1] = mask*ffsh[m*3+1];
    V[i*3+2] = mask*ffsh[m*3+2];
  }
  if (i == 0) {
    double qs = 0.0;
    for (int a = 0; a < N_ATOMS; ++a){ double qa=(double)q[a]; qs += qa*qa; }
    double area = cell_area(cell);
    double S = scal[0], S2 = scal[1], RR = scal[2];
    double recip = KE_C*PI_D*(S/(2.0*area) - S2/area);
    double realE = 0.5*KE_C*RR;
    double selfE = -ALPHA_C/sqrt(PI_D)*qs*KE_C;
    double Ec = recip + realE + selfE;
    out[4] = (float)Ec;
    for (int m = 0; m < 4; ++m) {
      double yb = scal[3+m];
      out[5+m] = (float)yb;
      out[m]   = (float)(Ec + yb);
    }
  }
  if (i < 4) {
    double f0 = ffsh[i*3+0], f1 = ffsh[i*3+1], f2 = ffsh[i*3+2];
    out[9+i] = (float)(f0*f0 + f1*f1 + f2*f2);
  }
}

// ---------------- finish pass2: fng = -2 * segsum(mask * Hv) ----------------
__global__ void finish2_kernel(const double* w8, const int* im, const int* film,
                               float* out){
  int i = threadIdx.x;
  __shared__ double gsh[256][3];
  double s0=0,s1=0,s2v=0;
  for (int c=0;c<8;++c){
    const double* w = w8 + c*768;
    s0 += w[i*3+0]; s1 += w[i*3+1]; s2v += w[i*3+2];
  }
  gsh[i][0]=s0; gsh[i][1]=s1; gsh[i][2]=s2v;
  __syncthreads();
  if (i < 12) {
    int mm = i/3, c = i%3;
    double s = 0.0;
    for (int a = 0; a < N_ATOMS; ++a)
      if (im[a] == mm && film[a] > 0) s += gsh[a][c];
    out[13+i] = (float)(-2.0*s);
  }
}

extern "C" void kernel_launch(void* const* d_in, const int* in_sizes, int n_in,
                              void* d_out, int out_size, void* d_ws, size_t ws_size,
                              hipStream_t stream){
  const float* R      = (const float*)d_in[0];
  const float* shiftv = (const float*)d_in[1];
  const float* q      = (const float*)d_in[2];
  const float* offs   = (const float*)d_in[3];
  const float* cell   = (const float*)d_in[4];
  const float* recipc = (const float*)d_in[5];
  const float* r0a    = (const float*)d_in[6];
  const float* na     = (const float*)d_in[7];
  const int*   ii     = (const int*)d_in[8];
  const int*   jj     = (const int*)d_in[9];
  const int*   im     = (const int*)d_in[10];
  const int*   film   = (const int*)d_in[11];
  float* out = (float*)d_out;

  double* ws   = (double*)d_ws;
  double* Rs   = ws;             // 768
  double* V    = ws + 768;       // 768
  double* scal = ws + 1536;      // 8: [0]=S [1]=S2 [2]=real [3..6]=born_mol
  double* g8   = ws + 1544;      // 8*768
  double* w8   = ws + 7688;      // 8*768
  float4* tab  = (float4*)(ws + 13832);  // 84*256 float4 = 344 KB

  // zero scal + g8 + w8
  hipMemsetAsync((void*)scal, 0, (size_t)(13832-1536)*sizeof(double), stream);
  hipLaunchKernelGGL(prep_kernel, dim3(1), dim3(256), 0, stream, R, shiftv, im, film, Rs);
  hipLaunchKernelGGL(ktab_kernel, dim3(84), dim3(256), 0, stream, Rs, recipc, tab);

  hipLaunchKernelGGL((pass_kernel<false>), dim3(KS_B+RE_B+BO_B+S2_B), dim3(256), 0, stream,
                     Rs, V, q, offs, r0a, na, ii, jj, im, recipc, cell, tab, g8, scal);
  hipLaunchKernelGGL(finish1_kernel, dim3(1), dim3(256), 0, stream,
                     g8, scal, q, cell, im, film, V, out);
  hipLaunchKernelGGL((pass_kernel<true>),  dim3(KS_B+RE_B+BO_B+S2_B), dim3(256), 0, stream,
                     Rs, V, q, offs, r0a, na, ii, jj, im, recipc, cell, tab, w8, scal);
  hipLaunchKernelGGL(finish2_kernel, dim3(1), dim3(256), 0, stream,
                     w8, im, film, out);
}